// Round 14
// baseline (150.850 us; speedup 1.0000x reference)
//
#include <hip/hip_runtime.h>
#include <hip/hip_bf16.h>

#define SPIX 1000
#define NCLS 21
#define PP (512*512)          // pixels per image, 2^18
#define NB_IMG 8
#define EPB (NCLS*PP)

// scatter geometry: block = 16384-pixel window x class-PAIR {2g, 2g+1}
// (class 20 rides as single-class blocks). Claim outcome depends only on the
// pixel window -> one claim round serves both classes.
#define PPIX 16384
#define PWPB (PP/PPIX)            // 16 pixel-windows per image
#define NCG 11                    // 10 pairs + 1 single
#define GX (PWPB*NCG)             // 176
#define DUMP 1000
#define SP21 12483                // 2^18 = 21*12483 + 1

// ws layout (floats)
#define R_OFF   0                      // [8][21][1000]
#define TR_OFF  (NB_IMG*NCLS*SPIX)     // [8]
#define NS_OFF  (TR_OFF + NB_IMG)      // [1] norm^2
#define CNT_OFF (NS_OFF + 1)           // [1] valid count
#define CTR_OFF (CNT_OFF + 1)          // [1] trace completion counter
#define WS_FLOATS (CTR_OFF + 1)

__device__ __forceinline__ void fatomic_add(float* p, float v) {
    unsafeAtomicAdd(p, v);   // native ds_add_f32 / global_atomic_add_f32
}

#define CLOBBER() asm volatile("" ::: "memory")

__global__ __launch_bounds__(512, 4) void scatter_kernel(const float* __restrict__ pred,
                                                         const int* __restrict__ seg,
                                                         const float* __restrict__ W,
                                                         float* __restrict__ Rout,
                                                         float* __restrict__ ns,
                                                         float* __restrict__ cnt) {
    if (blockIdx.y == NB_IMG) {            // -------- scalars blocks --------
        if (blockIdx.x < 88) {
            const float4* W4 = (const float4*)W;
            const int n4 = (NB_IMG * SPIX * SPIX) / 4;
            float s = 0.f;
            for (int i = blockIdx.x * 512 + threadIdx.x; i < n4; i += 88 * 512) {
                float4 v = W4[i];
                s += v.x*v.x + v.y*v.y + v.z*v.z + v.w*v.w;
            }
            #pragma unroll
            for (int off = 32; off; off >>= 1) s += __shfl_xor(s, off);
            if ((threadIdx.x & 63) == 0) fatomic_add(ns, s);
        } else {
            const int4* s4 = (const int4*)seg;
            const int n4 = (NB_IMG * PP) / 4;
            int c = 0;
            for (int i = (blockIdx.x - 88) * 512 + threadIdx.x; i < n4; i += 88 * 512) {
                int4 v = s4[i];
                c += ((unsigned)v.x < SPIX) + ((unsigned)v.y < SPIX) + ((unsigned)v.z < SPIX) + ((unsigned)v.w < SPIX);
            }
            float f = (float)c;
            #pragma unroll
            for (int off = 32; off; off >>= 1) f += __shfl_xor(f, off);
            if ((threadIdx.x & 63) == 0) fatomic_add(cnt, f);
        }
        return;
    }
    // -------- scatter blocks --------
    __shared__ float          Rw[8][2048];   // wave-private, interleaved [bin*2+cls], 64 KB
    __shared__ unsigned short Mk[8][1024];   // wave-private claim markers, 16 KB
    const int b   = blockIdx.y;
    const int pw  = blockIdx.x & (PWPB - 1);
    const int cg  = blockIdx.x >> 4;         // 0..10
    const int c0  = cg * 2;
    const bool two = (cg < 10);
    const int tid  = threadIdx.x;
    const int wave = tid >> 6;
    const unsigned short lane = (unsigned short)(tid & 63);
    const unsigned p0 = (unsigned)pw * PPIX;

    for (int i = tid; i < 8 * 2048; i += 512) ((float*)Rw)[i] = 0.f;
    __syncthreads();

    float*          wR = Rw[wave];
    unsigned short* wM = Mk[wave];

    const float* pb   = pred + (size_t)b * EPB;
    const int*   segb = seg + (size_t)b * PP + p0;

    // prefetch: seg int4 + 4 (or 8) pred gathers for pixel group E0
#define PREF(E0, SV, VA, VB) do {                                  \
        SV = *(const int4*)(segb + (E0));                          \
        unsigned f  = (unsigned)c0 * PP + p0 + (unsigned)(E0);     \
        unsigned sp = f / 21u;                                     \
        unsigned ch = f - sp * 21u;                                \
        _Pragma("unroll")                                          \
        for (int k = 0; k < 4; ++k) {                              \
            VA[k] = pb[(ch << 18) + sp];                           \
            if (two) {                                             \
                unsigned c1 = ch + 1u, s1 = sp + SP21;             \
                bool cr = (c1 == 21u);                             \
                c1 = cr ? 0u : c1; s1 += cr ? 1u : 0u;             \
                VB[k] = pb[(c1 << 18) + s1];                       \
            }                                                      \
            ch++;                                                  \
            bool cc = (ch == 21u);                                 \
            sp += cc ? 1u : 0u;                                    \
            ch  = cc ? 0u : ch;                                    \
        }                                                          \
    } while (0)

    int4 svN; float vNA[4], vNB[4];
    PREF(tid * 4, svN, vNA, vNB);                            // prologue

    for (int it = 0; it < PPIX / (512 * 4); ++it) {          // 8 iterations
        int4 sv = svN;
        float vA[4] = {vNA[0], vNA[1], vNA[2], vNA[3]};
        float vB[4] = {vNB[0], vNB[1], vNB[2], vNB[3]};
        if (it + 1 < PPIX / (512 * 4)) {
            PREF(((it + 1) * 512 + tid) * 4, svN, vNA, vNB);
        }
        int sA[4];
        #pragma unroll
        for (int k = 0; k < 4; ++k) {
            int s = (&sv.x)[k];
            sA[k] = ((unsigned)s < SPIX) ? s : DUMP;
        }
        // lane-local dedup (merge both classes' values with the same pattern)
        #pragma unroll
        for (int i = 0; i < 3; ++i)
            #pragma unroll
            for (int j = i + 1; j < 4; ++j) {
                bool e = (sA[j] == sA[i]) && (sA[i] != DUMP);
                vA[i] += e ? vA[j] : 0.f;
                vB[i] += e ? vB[j] : 0.f;
                sA[j]  = e ? DUMP  : sA[j];
            }
        // phase 1: claims (4 ds_write_b16) — one round serves both classes
        #pragma unroll
        for (int k = 0; k < 4; ++k) wM[sA[k]] = lane;
        CLOBBER();
        // phase 2: claim readback
        unsigned short rd[4];
        #pragma unroll
        for (int k = 0; k < 4; ++k) rd[k] = wM[sA[k]];
        CLOBBER();
        // phase 3: RMW reads (interleaved pair: banks 2s, 2s+1 — conflict-free pairing)
        float od0[4], od1[4];
        #pragma unroll
        for (int k = 0; k < 4; ++k) od0[k] = wR[sA[k] * 2];
        if (two) {
            #pragma unroll
            for (int k = 0; k < 4; ++k) od1[k] = wR[sA[k] * 2 + 1];
        }
        CLOBBER();
        // phase 4: winner writes (losers -> dump slots 2000/2001)
        bool lose1[4];
        #pragma unroll
        for (int k = 0; k < 4; ++k) {
            lose1[k] = (rd[k] != lane);
            wR[lose1[k] ? 2000 : (sA[k] * 2)] = od0[k] + vA[k];
        }
        if (two) {
            #pragma unroll
            for (int k = 0; k < 4; ++k)
                wR[lose1[k] ? 2001 : (sA[k] * 2 + 1)] = od1[k] + vB[k];
        }
        CLOBBER();   // order winner writes before fallbacks (in-order DS FIFO)
        // phase 5: loser fallback on the atomic pipe (~12% of lanes)
        #pragma unroll
        for (int k = 0; k < 4; ++k) {
            if (lose1[k]) {
                fatomic_add(&wR[sA[k] * 2], vA[k]);
                if (two) fatomic_add(&wR[sA[k] * 2 + 1], vB[k]);
            }
        }
    }
#undef PREF
    __syncthreads();

    // merge 8 wave copies, one global atomic per (bin, cls)
    float* Rb = Rout + (size_t)b * NCLS * SPIX + (size_t)c0 * SPIX;
    for (int i = tid; i < 2000; i += 512) {
        int cls = i & 1, s = i >> 1;
        if (cls && !two) continue;
        float a = 0.f;
        #pragma unroll
        for (int w = 0; w < 8; ++w) a += Rw[w][i];
        if (a != 0.f) fatomic_add(&Rb[cls * SPIX + s], a);
    }
}

// trace[b] = sum_{s,t} L[b,s,t] * sum_c R[b,c,s]*R[b,c,t]; last block finalizes.
__global__ __launch_bounds__(512) void trace_kernel(const float* __restrict__ L,
                                                    const float* __restrict__ R,
                                                    float* __restrict__ traces,
                                                    const float* __restrict__ ns,
                                                    const float* __restrict__ cnt,
                                                    unsigned* __restrict__ ctr,
                                                    float* __restrict__ out) {
    __shared__ float Rl[NCLS * SPIX];   // 84 KB
    const int b = blockIdx.y;
    const float* Rb = R + (size_t)b * NCLS * SPIX;
    for (int i = threadIdx.x; i < NCLS * SPIX; i += 512) Rl[i] = Rb[i];
    __syncthreads();

    const int wave = threadIdx.x >> 6;
    const int lane = threadIdx.x & 63;
    const float* Lb = L + (size_t)b * SPIX * SPIX;

    const int s0 = (blockIdx.x * 8 + wave) * 4;
    bool val[4];
    const float4* Lr[4];
    #pragma unroll
    for (int r = 0; r < 4; ++r) {
        int sr = s0 + r;
        val[r] = sr < SPIX;
        Lr[r] = (const float4*)(Lb + (size_t)(val[r] ? sr : (SPIX - 1)) * SPIX);
    }

    float acc[4][NCLS];
    #pragma unroll
    for (int r = 0; r < 4; ++r)
        #pragma unroll
        for (int c = 0; c < NCLS; ++c) acc[r][c] = 0.f;

    #pragma unroll
    for (int it = 0; it < 4; ++it) {
        int idx = it * 64 + lane;
        if (idx < SPIX / 4) {
            float4 l[4];
            #pragma unroll
            for (int r = 0; r < 4; ++r)
                l[r] = val[r] ? Lr[r][idx] : make_float4(0.f, 0.f, 0.f, 0.f);
            #pragma unroll
            for (int c = 0; c < NCLS; ++c) {
                float4 rr = *(const float4*)&Rl[c * SPIX + idx * 4];
                #pragma unroll
                for (int r = 0; r < 4; ++r)
                    acc[r][c] += l[r].x * rr.x + l[r].y * rr.y + l[r].z * rr.z + l[r].w * rr.w;
            }
        }
    }

    float partial = 0.f;
    #pragma unroll
    for (int c = 0; c < NCLS; ++c)
        #pragma unroll
        for (int r = 0; r < 4; ++r)
            if (val[r]) partial += Rl[c * SPIX + s0 + r] * acc[r][c];

    #pragma unroll
    for (int off = 32; off; off >>= 1) partial += __shfl_xor(partial, off);
    if (lane == 0) fatomic_add(&traces[b], partial);

    __syncthreads();
    if (threadIdx.x == 0) {
        __threadfence();
        unsigned old = atomicAdd(ctr, 1u);
        if (old == 32u * NB_IMG - 1u) {
            __threadfence();
            float t = 0.f;
            #pragma unroll
            for (int i = 0; i < NB_IMG; ++i)
                t += __hip_atomic_load(&traces[i], __ATOMIC_RELAXED, __HIP_MEMORY_SCOPE_AGENT);
            float denom = cnt[0] + 1e-16f;
            out[0] = (2.f / sqrtf(ns[0])) * t / (denom * denom) / (float)NB_IMG;
        }
    }
}

extern "C" void kernel_launch(void* const* d_in, const int* in_sizes, int n_in,
                              void* d_out, int out_size, void* d_ws, size_t ws_size,
                              hipStream_t stream) {
    const float* pred = (const float*)d_in[0];
    const float* Wc   = (const float*)d_in[1];
    const float* Lc   = (const float*)d_in[2];
    const int*   seg  = (const int*)d_in[3];
    float* ws = (float*)d_ws;
    float* out = (float*)d_out;

    hipMemsetAsync(d_ws, 0, WS_FLOATS * sizeof(float), stream);

    scatter_kernel<<<dim3(GX, NB_IMG + 1), 512, 0, stream>>>(
        pred, seg, Wc, ws + R_OFF, ws + NS_OFF, ws + CNT_OFF);

    trace_kernel<<<dim3(32, NB_IMG), 512, 0, stream>>>(
        Lc, ws + R_OFF, ws + TR_OFF, ws + NS_OFF, ws + CNT_OFF,
        (unsigned*)(ws + CTR_OFF), out);
}